// Round 7
// baseline (459.312 us; speedup 1.0000x reference)
//
#include <hip/hip_runtime.h>
#include <hip/hip_bf16.h>
#include <math.h>

#define B_      256
#define DA      1024
#define S_      8
#define DK      128
#define NKEYS   100000
#define KMAX    32
#define KTOT    1024            // S_*DK flattened reduction dim
#define BN      128             // n-tile per block (pass_b2)
#define NBLK    ((NKEYS + BN - 1) / BN)

typedef __attribute__((ext_vector_type(8))) short short8;
typedef __attribute__((ext_vector_type(4))) float f32x4;

typedef const __attribute__((address_space(1))) unsigned gu32;
typedef __attribute__((address_space(3))) unsigned lu32;
#define GLOAD_LDS16(g, s) __builtin_amdgcn_global_load_lds((gu32*)(g), (lu32*)(s), 16, 0, 0)

__device__ __forceinline__ float bf16_up(short h) {
    union { unsigned u; float f; } cv;
    cv.u = ((unsigned)(unsigned short)h) << 16;
    return cv.f;
}

// ---------------------------------------------------------------------------
// Pass A: queries = einsum('ska,ba->bsk', W_Q, z), L2-normalized (fp64 acc).
// (unchanged -- QT/Qb must stay bit-identical across rounds)
// ---------------------------------------------------------------------------
__global__ __launch_bounds__(128) void pass_a_kernel(
    const float* __restrict__ z, const float* __restrict__ wq,
    float* __restrict__ QT, __hip_bfloat16* __restrict__ Qb)
{
    const int b = blockIdx.x;
    const int s = blockIdx.y;
    __shared__ float zsh[DA];
    for (int i = threadIdx.x; i < DA; i += 128) zsh[i] = z[b * DA + i];
    __syncthreads();
    const int k = threadIdx.x;
    const float* wrow = wq + (size_t)(s * DK + k) * DA;
    double acc = 0.0;
    #pragma unroll 4
    for (int a = 0; a < DA; a += 4) {
        const float4 w4 = *reinterpret_cast<const float4*>(wrow + a);
        acc += (double)w4.x * (double)zsh[a + 0];
        acc += (double)w4.y * (double)zsh[a + 1];
        acc += (double)w4.z * (double)zsh[a + 2];
        acc += (double)w4.w * (double)zsh[a + 3];
    }
    double sq = acc * acc;
    #pragma unroll
    for (int off = 32; off > 0; off >>= 1) sq += __shfl_down(sq, off);
    __shared__ double part[2];
    if ((threadIdx.x & 63) == 0) part[threadIdx.x >> 6] = sq;
    __syncthreads();
    const double ss  = part[0] + part[1];
    const double inv = 1.0 / (sqrt(ss) + 1e-8);
    const float qv = (float)(acc * inv);
    QT[(size_t)(s * DK + k) * B_ + b] = qv;
    Qb[(size_t)b * KTOT + s * DK + k] = __float2bfloat16(qv);
}

// ---------------------------------------------------------------------------
// Pass B2 (fused norms+scale+GEMM): reads keys ONCE. Per aspect:
//   stage fp32 slab [128n][128k] (64KB, gload_lds) -> norms (16-lane fp64
//   butterfly, bit-identical to old pass_k; writes F) -> cvt bf16*f into
//   swizzled B tiles (bit-identical values to old Kb) -> 2 MFMA halves.
// slab(s+1) prefetch rides across half-0 via counted vmcnt(8) (FIFO: A's 4
// loads retire first). LDS: A 32K + B 32K + slab 64K = 128K, 1 block/CU.
// ---------------------------------------------------------------------------
#define A_OFF    0
#define B_OFF    32768
#define SLAB_OFF 65536

__global__ __launch_bounds__(512, 2) void pass_b2_kernel(
    const float* __restrict__ keys, const float* __restrict__ aw,
    const __hip_bfloat16* __restrict__ Qb,
    float* __restrict__ F, __hip_bfloat16* __restrict__ C)
{
    __shared__ __align__(16) char smem[131072];
    __shared__ float f_sh[BN];
    const int n0 = blockIdx.x * BN;
    const int tid = threadIdx.x;
    const int w = tid >> 6, l = tid & 63;
    const int ln = l & 15, lk = l >> 4;
    const int wm = w >> 1, wn = w & 1;           // 4M x 2N wave grid
    const int sl = l & 7, lr = l >> 3;           // A-staging slot / row
    const int g16 = tid >> 4, l16 = tid & 15;    // norm groups

    // softmax(aspect_weights) -- identical fp32 ops to old pass_k
    float e[S_];
    float mxw = aw[0];
    #pragma unroll
    for (int i = 1; i < S_; ++i) mxw = fmaxf(mxw, aw[i]);
    float se = 0.f;
    #pragma unroll
    for (int i = 0; i < S_; ++i) { e[i] = expf(aw[i] - mxw); se += e[i]; }

    f32x4 acc[4][4];
    #pragma unroll
    for (int i = 0; i < 4; ++i)
        #pragma unroll
        for (int j = 0; j < 4; ++j) acc[i][j] = (f32x4){0.f, 0.f, 0.f, 0.f};

    const char* qb = (const char*)Qb;

    auto stage_slab = [&](int sa) {
        const float* kb = keys + (size_t)sa * NKEYS * DK;
        #pragma unroll
        for (int i = 0; i < 8; ++i) {
            const int j = w + 8 * i;             // chunk 0..63 (2 rows each)
            int gn = n0 + j * 2 + (l >> 5);
            gn = gn < NKEYS ? gn : NKEYS - 1;    // clamp: stay in-bounds
            const float* g = kb + (size_t)gn * DK + (l & 31) * 4;
            GLOAD_LDS16(g, smem + SLAB_OFF + j * 1024);
        }
    };
    auto stage_a = [&](int kc) {
        #pragma unroll
        for (int i = 0; i < 4; ++i) {
            const int j = w + 8 * i;             // chunk 0..31
            const int bq = j * 8 + lr;           // query row 0..255
            const char* g = qb + ((size_t)bq * KTOT + kc + ((sl ^ (bq & 7)) << 3)) * 2;
            GLOAD_LDS16(g, smem + A_OFF + j * 1024);
        }
    };

    stage_slab(0);
    asm volatile("s_waitcnt vmcnt(0)" ::: "memory");
    __syncthreads();

    for (int s = 0; s < S_; ++s) {
        const float wgt = e[s] / se;
        // ---- norms: 4 passes x 32 rows, 16 lanes/row (pass_k-identical) ----
        #pragma unroll
        for (int p = 0; p < 4; ++p) {
            const int r = p * 32 + g16;
            const float* srow = (const float*)(smem + SLAB_OFF + r * 512) + l16 * 8;
            const float4 r0 = *reinterpret_cast<const float4*>(srow);
            const float4 r1 = *reinterpret_cast<const float4*>(srow + 4);
            double sq = (double)r0.x * r0.x + (double)r0.y * r0.y +
                        (double)r0.z * r0.z + (double)r0.w * r0.w +
                        (double)r1.x * r1.x + (double)r1.y * r1.y +
                        (double)r1.z * r1.z + (double)r1.w * r1.w;
            #pragma unroll
            for (int off = 1; off < 16; off <<= 1) sq += __shfl_xor(sq, off);
            const float f = (float)((double)wgt / (sqrt(sq) + 1e-8));
            if (l16 == 0) {
                f_sh[r] = f;
                const int n = n0 + r;
                if (n < NKEYS) F[(size_t)s * NKEYS + n] = f;
            }
        }
        __syncthreads();
        // ---- cvt: slab fp32 -> bf16*f into swizzled B tiles (both halves) ----
        #pragma unroll
        for (int c = 0; c < 4; ++c) {
            const int u = tid + c * 512;         // 0..2047 slots
            const int h = u >> 10;
            const int rem = u & 1023;
            const int nr = rem >> 3, slot = rem & 7;
            const float* sp = (const float*)(smem + SLAB_OFF + nr * 512 + h * 256 + slot * 32);
            const float4 v0 = *reinterpret_cast<const float4*>(sp);
            const float4 v1 = *reinterpret_cast<const float4*>(sp + 4);
            const float f = f_sh[nr];
            const float vv[8] = {v0.x, v0.y, v0.z, v0.w, v1.x, v1.y, v1.z, v1.w};
            short8 pk;
            #pragma unroll
            for (int ee = 0; ee < 8; ++ee) {
                __hip_bfloat16 hb = __float2bfloat16(vv[ee] * f);
                pk[ee] = *reinterpret_cast<short*>(&hb);
            }
            *reinterpret_cast<short8*>(smem + B_OFF + h * 16384 + nr * 128 +
                                       ((slot ^ (nr & 7)) << 4)) = pk;
        }
        __syncthreads();                          // B ready; slab region free; vm drained

        #pragma unroll
        for (int h = 0; h < 2; ++h) {
            stage_a(s * DK + h * 64);
            if (h == 0) {
                stage_slab(s < 7 ? s + 1 : 7);    // prefetch rides across half-0
                asm volatile("s_waitcnt vmcnt(8)" ::: "memory");  // retire A only
            } else {
                asm volatile("s_waitcnt vmcnt(0)" ::: "memory");  // drain slab+A
            }
            __builtin_amdgcn_sched_barrier(0);
            __builtin_amdgcn_s_barrier();
            __builtin_amdgcn_sched_barrier(0);
            const char* bbase = smem + B_OFF + h * 16384;
            #pragma unroll
            for (int kw = 0; kw < 2; ++kw) {
                const int slot = kw * 4 + lk;
                short8 af[4], bf[4];
                #pragma unroll
                for (int mi = 0; mi < 4; ++mi) {
                    const int bq = wm * 64 + mi * 16 + ln;
                    af[mi] = *reinterpret_cast<const short8*>(
                        smem + A_OFF + bq * 128 + ((slot ^ (bq & 7)) << 4));
                }
                #pragma unroll
                for (int nf = 0; nf < 4; ++nf) {
                    const int nr = wn * 64 + nf * 16 + ln;
                    bf[nf] = *reinterpret_cast<const short8*>(
                        bbase + nr * 128 + ((slot ^ (nr & 7)) << 4));
                }
                #pragma unroll
                for (int mi = 0; mi < 4; ++mi)
                    #pragma unroll
                    for (int nf = 0; nf < 4; ++nf)
                        acc[mi][nf] = __builtin_amdgcn_mfma_f32_16x16x32_bf16(
                            af[mi], bf[nf], acc[mi][nf], 0, 0, 0);
            }
            __builtin_amdgcn_s_barrier();         // A (and B) readers done
        }
    }
    // ---- C store: row=(lane>>4)*4+reg, col=lane&15 (m89-verified layout) ----
    #pragma unroll
    for (int mi = 0; mi < 4; ++mi) {
        #pragma unroll
        for (int nf = 0; nf < 4; ++nf) {
            const int n = n0 + wn * 64 + nf * 16 + ln;
            if (n < NKEYS) {
                #pragma unroll
                for (int r = 0; r < 4; ++r) {
                    const int bq = wm * 64 + mi * 16 + lk * 4 + r;
                    C[(size_t)bq * NKEYS + n] = __float2bfloat16(acc[mi][nf][r]);
                }
            }
        }
    }
}

// ---------------------------------------------------------------------------
// Pass C: R6 structure; serial 1024-bin cumsum replaced by a two-level
// wave-parallel suffix scan producing the IDENTICAL threshold expression.
// ---------------------------------------------------------------------------
#define MAXC 2048
#define MARGIN 1e-2f
#define HB 1024
#define NV8 12500               // short8's per row (100000/8)
#define CTH 1024                // threads

__global__ __launch_bounds__(1024) void pass_c_kernel(
    const __hip_bfloat16* __restrict__ C, const float* __restrict__ keys,
    const float* __restrict__ QT, const float* __restrict__ F,
    const float* __restrict__ tau_p, const float* __restrict__ lam_p,
    const unsigned char* __restrict__ warm_p, float* __restrict__ out)
{
    const int b = blockIdx.x, tid = threadIdx.x;
    __shared__ float redA[16], redB[16], redC[16];
    __shared__ unsigned hist[HB];
    __shared__ double cval[MAXC];
    __shared__ int cidx[MAXC];
    __shared__ int cnt;
    __shared__ float sh_thr, sh_lo, sh_iw;
    __shared__ int sh_done;
    __shared__ float sh_stat[3];
    __shared__ double topv[KMAX];
    __shared__ int topi[KMAX];

    const __hip_bfloat16* crow = C + (size_t)b * NKEYS;

    // ---- phase 1: mean / var / max (streaming short8) ----
    float sm = 0.f, sq = 0.f, mx = -2.f;
    for (int i = tid; i < NV8; i += CTH) {
        const short8 v8 = *reinterpret_cast<const short8*>(crow + i * 8);
        #pragma unroll
        for (int e = 0; e < 8; ++e) {
            const float v = bf16_up(v8[e]);
            sm += v; sq += v * v; mx = fmaxf(mx, v);
        }
    }
    #pragma unroll
    for (int off = 32; off > 0; off >>= 1) {
        sm += __shfl_down(sm, off);
        sq += __shfl_down(sq, off);
        mx = fmaxf(mx, __shfl_down(mx, off));
    }
    if ((tid & 63) == 0) { redA[tid >> 6] = sm; redB[tid >> 6] = sq; redC[tid >> 6] = mx; }
    __syncthreads();
    if (tid == 0) {
        float S1 = 0.f, S2 = 0.f, M = -2.f;
        #pragma unroll
        for (int i = 0; i < 16; ++i) { S1 += redA[i]; S2 += redB[i]; M = fmaxf(M, redC[i]); }
        const float mu = S1 / NKEYS;
        sh_stat[0] = mu;
        sh_stat[1] = sqrtf(fmaxf(S2 / NKEYS - mu * mu, 1e-12f));
        sh_stat[2] = M;
    }
    __syncthreads();
    const float mu = sh_stat[0], sg = sh_stat[1], rmax = sh_stat[2];

    // ---- phase 2: adaptive tail histogram + PARALLEL suffix scan ----
    for (int attempt = 0; attempt < 3; ++attempt) {
        if (tid == 0) {
            float lo = (attempt == 0) ? (mu + 2.5f * sg)
                     : (attempt == 1) ? mu : -1.1f;
            lo = fminf(lo, rmax - 1e-6f);
            const float range = fmaxf(rmax + 1e-6f - lo, 1e-6f);
            sh_lo = lo;
            sh_iw = (float)HB / range;
        }
        for (int i = tid; i < HB; i += CTH) hist[i] = 0u;
        __syncthreads();
        const float lo = sh_lo, iw = sh_iw;
        for (int i = tid; i < NV8; i += CTH) {
            const short8 v8 = *reinterpret_cast<const short8*>(crow + i * 8);
            #pragma unroll
            for (int e = 0; e < 8; ++e) {
                const float v = bf16_up(v8[e]);
                if (v >= lo) {
                    const int bin = min((int)((v - lo) * iw), HB - 1);
                    atomicAdd(&hist[bin], 1u);
                }
            }
        }
        __syncthreads();
        if (tid < 64) {
            // lane l owns bins [l*16, l*16+16)
            unsigned csum = 0;
            #pragma unroll
            for (int j = 0; j < 16; ++j) csum += hist[tid * 16 + j];
            unsigned S = csum;                    // inclusive suffix over lanes
            #pragma unroll
            for (int off = 1; off < 64; off <<= 1) {
                const unsigned u = __shfl_down(S, off);
                if (tid + off < 64) S += u;
            }
            const unsigned long long mk = __ballot(S >= (unsigned)KMAX);
            if (mk == 0ull) {
                if (tid == 0) sh_done = 0;
            } else {
                const int cstar = 63 - __clzll(mk);
                const unsigned above = (cstar < 63) ? __shfl(S, cstar + 1) : 0u;
                unsigned v2 = (tid < 16) ? hist[cstar * 16 + tid] : 0u;
                unsigned S2 = v2;
                #pragma unroll
                for (int off = 1; off < 64; off <<= 1) {
                    const unsigned u = __shfl_down(S2, off);
                    if (tid + off < 64) S2 += u;
                }
                S2 += above;
                const unsigned long long mk2 = __ballot(S2 >= (unsigned)KMAX);
                const int hi = 63 - __clzll(mk2);
                const int t = cstar * 16 + hi;
                if (tid == 0) {
                    sh_thr = lo + (float)t / sh_iw - MARGIN;   // R6-identical expression
                    sh_done = 1;
                }
            }
        }
        __syncthreads();
        if (sh_done) break;
    }

    // ---- phase 3: compact candidates (streaming) ----
    if (tid == 0) cnt = 0;
    __syncthreads();
    const float ct = sh_thr;
    for (int i = tid; i < NV8; i += CTH) {
        const short8 v8 = *reinterpret_cast<const short8*>(crow + i * 8);
        #pragma unroll
        for (int e = 0; e < 8; ++e) {
            if (bf16_up(v8[e]) >= ct) {
                const int p = atomicAdd(&cnt, 1);
                if (p < MAXC) cidx[p] = i * 8 + e;
            }
        }
    }
    __syncthreads();
    const int m = min(cnt, MAXC);

    // ---- phase 4: fp64 exact re-rank, one candidate per wave (16 waves) ----
    const int wave = tid >> 6, lane = tid & 63;
    const int si = lane >> 3, kg = lane & 7;
    for (int c = wave; c < m; c += 16) {
        const int n = cidx[c];
        const float f = F[(size_t)si * NKEYS + n];
        const float* krow = keys + ((size_t)si * NKEYS + n) * DK + kg * 16;
        const float4 k0 = *reinterpret_cast<const float4*>(krow + 0);
        const float4 k1 = *reinterpret_cast<const float4*>(krow + 4);
        const float4 k2 = *reinterpret_cast<const float4*>(krow + 8);
        const float4 k3 = *reinterpret_cast<const float4*>(krow + 12);
        const float kf[16] = {k0.x, k0.y, k0.z, k0.w, k1.x, k1.y, k1.z, k1.w,
                              k2.x, k2.y, k2.z, k2.w, k3.x, k3.y, k3.z, k3.w};
        double acc = 0.0;
        #pragma unroll
        for (int j = 0; j < 16; ++j) {
            const float q = QT[(size_t)(si * DK + kg * 16 + j) * B_ + b];
            acc += (double)q * ((double)kf[j] * (double)f);
        }
        #pragma unroll
        for (int off = 1; off < 64; off <<= 1) acc += __shfl_xor(acc, off);
        if (lane == 0) cval[c] = acc;
    }
    __syncthreads();

    // ---- phase 5: single-wave exact top-32 (desc value, ties -> asc index) ----
    if (tid < 64) {
        for (int r = 0; r < KMAX; ++r) {
            double bv = -1e300; int bi = 0x7fffffff; int bp = -1;
            for (int c = tid; c < m; c += 64) {
                const double v = cval[c]; const int ix = cidx[c];
                if (v > bv || (v == bv && ix < bi)) { bv = v; bi = ix; bp = c; }
            }
            #pragma unroll
            for (int off = 32; off > 0; off >>= 1) {
                const double ov = __shfl_xor(bv, off);
                const int oi = __shfl_xor(bi, off);
                const int op = __shfl_xor(bp, off);
                if (ov > bv || (ov == bv && oi < bi)) { bv = ov; bi = oi; bp = op; }
            }
            if (tid == 0) { topv[r] = bv; topi[r] = bi; if (bp >= 0) cval[bp] = -1e301; }
        }
        if (tid == 0) {
            const float lamv = lam_p[0];
            const float tauv = tau_p[0];
            const bool warm = warm_p[0] != 0;
            float al[KMAX];
            float ssum = 0.f;
            if (warm) {
                const float x0 = (float)topv[0] / 0.1f;
                for (int i = 0; i < KMAX; ++i) {
                    const float e = expf((float)topv[i] / 0.1f - x0);
                    al[i] = e; ssum += e;
                }
            } else {
                for (int i = 0; i < KMAX; ++i) {
                    const float v = (float)topv[i];
                    const float g = 1.0f / (1.0f + expf(-(lamv * (v - tauv))));
                    const float rr = g * expf(v / 0.1f);
                    al[i] = rr; ssum += rr;
                }
            }
            for (int i = 0; i < KMAX; ++i) {
                out[b * KMAX + i] = al[i] / ssum;
                out[B_ * KMAX + b * KMAX + i] = (float)topi[i];
            }
        }
    }
}

// ---------------------------------------------------------------------------
extern "C" void kernel_launch(void* const* d_in, const int* in_sizes, int n_in,
                              void* d_out, int out_size, void* d_ws, size_t ws_size,
                              hipStream_t stream) {
    const float* z    = (const float*)d_in[0];
    const float* keys = (const float*)d_in[1];
    const float* wq   = (const float*)d_in[2];
    const float* aw   = (const float*)d_in[3];
    const float* tau  = (const float*)d_in[4];
    const float* lam  = (const float*)d_in[5];
    const unsigned char* warm = (const unsigned char*)d_in[6];
    float* out = (float*)d_out;

    char* ws = (char*)d_ws;
    float* QT           = (float*)ws;                          // @0       1.0 MB
    float* F            = (float*)(ws + (1 << 20));            // @1MB     3.2 MB
    __hip_bfloat16* Qb  = (__hip_bfloat16*)(ws + (8 << 20));   // @8MB     0.5 MB
    __hip_bfloat16* C   = (__hip_bfloat16*)(ws + ((size_t)232 << 20)); // @232MB 51.2 MB

    pass_a_kernel<<<dim3(B_, S_), 128, 0, stream>>>(z, wq, QT, Qb);
    pass_b2_kernel<<<dim3(NBLK), 512, 0, stream>>>(keys, aw, Qb, F, C);
    pass_c_kernel<<<dim3(B_), 1024, 0, stream>>>(C, keys, QT, F, tau, lam, warm, out);
}

// Round 8
// 453.475 us; speedup vs baseline: 1.0129x; 1.0129x over previous
//
#include <hip/hip_runtime.h>
#include <hip/hip_bf16.h>
#include <math.h>

#define B_      256
#define DA      1024
#define S_      8
#define DK      128
#define NKEYS   100000
#define KMAX    32
#define KTOT    1024            // S_*DK flattened reduction dim
#define BN      128             // n-tile per block (pass_b2)
#define NBLK    ((NKEYS + BN - 1) / BN)

typedef __attribute__((ext_vector_type(8))) short short8;
typedef __attribute__((ext_vector_type(4))) float f32x4;

typedef const __attribute__((address_space(1))) unsigned gu32;
typedef __attribute__((address_space(3))) unsigned lu32;
#define GLOAD_LDS16(g, s) __builtin_amdgcn_global_load_lds((gu32*)(g), (lu32*)(s), 16, 0, 0)

__device__ __forceinline__ float bf16_up(short h) {
    union { unsigned u; float f; } cv;
    cv.u = ((unsigned)(unsigned short)h) << 16;
    return cv.f;
}

// ---------------------------------------------------------------------------
// Pass A: queries = einsum('ska,ba->bsk', W_Q, z), L2-normalized (fp64 acc).
// (unchanged -- QT/Qb must stay bit-identical across rounds)
// ---------------------------------------------------------------------------
__global__ __launch_bounds__(128) void pass_a_kernel(
    const float* __restrict__ z, const float* __restrict__ wq,
    float* __restrict__ QT, __hip_bfloat16* __restrict__ Qb)
{
    const int b = blockIdx.x;
    const int s = blockIdx.y;
    __shared__ float zsh[DA];
    for (int i = threadIdx.x; i < DA; i += 128) zsh[i] = z[b * DA + i];
    __syncthreads();
    const int k = threadIdx.x;
    const float* wrow = wq + (size_t)(s * DK + k) * DA;
    double acc = 0.0;
    #pragma unroll 4
    for (int a = 0; a < DA; a += 4) {
        const float4 w4 = *reinterpret_cast<const float4*>(wrow + a);
        acc += (double)w4.x * (double)zsh[a + 0];
        acc += (double)w4.y * (double)zsh[a + 1];
        acc += (double)w4.z * (double)zsh[a + 2];
        acc += (double)w4.w * (double)zsh[a + 3];
    }
    double sq = acc * acc;
    #pragma unroll
    for (int off = 32; off > 0; off >>= 1) sq += __shfl_down(sq, off);
    __shared__ double part[2];
    if ((threadIdx.x & 63) == 0) part[threadIdx.x >> 6] = sq;
    __syncthreads();
    const double ss  = part[0] + part[1];
    const double inv = 1.0 / (sqrt(ss) + 1e-8);
    const float qv = (float)(acc * inv);
    QT[(size_t)(s * DK + k) * B_ + b] = qv;
    Qb[(size_t)b * KTOT + s * DK + k] = __float2bfloat16(qv);
}

// ---------------------------------------------------------------------------
// Pass B2 v2 (fused norms+scale+GEMM, reg-staged): reads keys ONCE, no slab.
// Per aspect: 4 passes where each 16-lane group loads its key row into REGS,
// computes the pass_k-identical fp64 norm butterfly (every lane ends with f),
// converts its own 8 values, and does ONE swizzled ds_write_b128 into the
// B tile. LDS = A 32K + B 32K = 64K -> 2 blocks/CU (4 waves/SIMD); the
// co-resident block's compute hides the HBM key-load latency.
// Identical op order everywhere -> F and scores bit-identical to R7.
// ---------------------------------------------------------------------------
#define A_OFF    0
#define B_OFF    32768

__global__ __launch_bounds__(512) void pass_b2_kernel(
    const float* __restrict__ keys, const float* __restrict__ aw,
    const __hip_bfloat16* __restrict__ Qb,
    float* __restrict__ F, __hip_bfloat16* __restrict__ C)
{
    __shared__ __align__(16) char smem[65536];
    const int n0 = blockIdx.x * BN;
    const int tid = threadIdx.x;
    const int w = tid >> 6, l = tid & 63;
    const int ln = l & 15, lk = l >> 4;
    const int wm = w >> 1, wn = w & 1;           // 4M x 2N wave grid
    const int sl = l & 7, lr = l >> 3;           // A-staging slot / row
    const int g16 = tid >> 4, l16 = tid & 15;    // norm groups

    // softmax(aspect_weights) -- identical fp32 ops to old pass_k
    float e[S_];
    float mxw = aw[0];
    #pragma unroll
    for (int i = 1; i < S_; ++i) mxw = fmaxf(mxw, aw[i]);
    float se = 0.f;
    #pragma unroll
    for (int i = 0; i < S_; ++i) { e[i] = expf(aw[i] - mxw); se += e[i]; }

    f32x4 acc[4][4];
    #pragma unroll
    for (int i = 0; i < 4; ++i)
        #pragma unroll
        for (int j = 0; j < 4; ++j) acc[i][j] = (f32x4){0.f, 0.f, 0.f, 0.f};

    const char* qb = (const char*)Qb;

    auto stage_a = [&](int kc) {
        #pragma unroll
        for (int i = 0; i < 4; ++i) {
            const int j = w + 8 * i;             // chunk 0..31
            const int bq = j * 8 + lr;           // query row 0..255
            const char* g = qb + ((size_t)bq * KTOT + kc + ((sl ^ (bq & 7)) << 3)) * 2;
            GLOAD_LDS16(g, smem + A_OFF + j * 1024);
        }
    };

    for (int s = 0; s < S_; ++s) {
        const float wgt = e[s] / se;
        const float* kbase = keys + (size_t)s * NKEYS * DK;
        // ---- norm+cvt+write: 4 passes x 32 rows, 16 lanes/row, reg-staged ----
        #pragma unroll
        for (int p = 0; p < 4; ++p) {
            const int r = p * 32 + g16;          // 0..127
            const int nreal = n0 + r;
            const int n = nreal < NKEYS ? nreal : NKEYS - 1;   // clamp in-bounds
            const float* srow = kbase + (size_t)n * DK + l16 * 8;
            const float4 r0 = *reinterpret_cast<const float4*>(srow);
            const float4 r1 = *reinterpret_cast<const float4*>(srow + 4);
            double sq = (double)r0.x * r0.x + (double)r0.y * r0.y +
                        (double)r0.z * r0.z + (double)r0.w * r0.w +
                        (double)r1.x * r1.x + (double)r1.y * r1.y +
                        (double)r1.z * r1.z + (double)r1.w * r1.w;
            #pragma unroll
            for (int off = 1; off < 16; off <<= 1) sq += __shfl_xor(sq, off);
            const float f = (float)((double)wgt / (sqrt(sq) + 1e-8));
            if (l16 == 0 && nreal < NKEYS) F[(size_t)s * NKEYS + nreal] = f;
            const float vv[8] = {r0.x, r0.y, r0.z, r0.w, r1.x, r1.y, r1.z, r1.w};
            short8 pk;
            #pragma unroll
            for (int ee = 0; ee < 8; ++ee) {
                __hip_bfloat16 hb = __float2bfloat16(vv[ee] * f);
                pk[ee] = *reinterpret_cast<short*>(&hb);
            }
            const int h = l16 >> 3, slot = l16 & 7;
            *reinterpret_cast<short8*>(smem + B_OFF + h * 16384 + r * 128 +
                                       ((slot ^ (r & 7)) << 4)) = pk;
        }
        __syncthreads();                          // B tiles visible to all waves

        #pragma unroll
        for (int h = 0; h < 2; ++h) {
            stage_a(s * DK + h * 64);
            asm volatile("s_waitcnt vmcnt(0)" ::: "memory");
            __builtin_amdgcn_sched_barrier(0);
            __builtin_amdgcn_s_barrier();
            __builtin_amdgcn_sched_barrier(0);
            const char* bbase = smem + B_OFF + h * 16384;
            #pragma unroll
            for (int kw = 0; kw < 2; ++kw) {
                const int slot = kw * 4 + lk;
                short8 af[4], bf[4];
                #pragma unroll
                for (int mi = 0; mi < 4; ++mi) {
                    const int bq = wm * 64 + mi * 16 + ln;
                    af[mi] = *reinterpret_cast<const short8*>(
                        smem + A_OFF + bq * 128 + ((slot ^ (bq & 7)) << 4));
                }
                #pragma unroll
                for (int nf = 0; nf < 4; ++nf) {
                    const int nr = wn * 64 + nf * 16 + ln;
                    bf[nf] = *reinterpret_cast<const short8*>(
                        bbase + nr * 128 + ((slot ^ (nr & 7)) << 4));
                }
                #pragma unroll
                for (int mi = 0; mi < 4; ++mi)
                    #pragma unroll
                    for (int nf = 0; nf < 4; ++nf)
                        acc[mi][nf] = __builtin_amdgcn_mfma_f32_16x16x32_bf16(
                            af[mi], bf[nf], acc[mi][nf], 0, 0, 0);
            }
            __builtin_amdgcn_s_barrier();         // A/B readers done before rewrite
        }
    }
    // ---- C store: row=(lane>>4)*4+reg, col=lane&15 (m89-verified layout) ----
    #pragma unroll
    for (int mi = 0; mi < 4; ++mi) {
        #pragma unroll
        for (int nf = 0; nf < 4; ++nf) {
            const int n = n0 + wn * 64 + nf * 16 + ln;
            if (n < NKEYS) {
                #pragma unroll
                for (int r = 0; r < 4; ++r) {
                    const int bq = wm * 64 + mi * 16 + lk * 4 + r;
                    C[(size_t)bq * NKEYS + n] = __float2bfloat16(acc[mi][nf][r]);
                }
            }
        }
    }
}

// ---------------------------------------------------------------------------
// Pass C: unchanged from round 7 (parallel suffix scan; exact-rank frozen).
// ---------------------------------------------------------------------------
#define MAXC 2048
#define MARGIN 1e-2f
#define HB 1024
#define NV8 12500               // short8's per row (100000/8)
#define CTH 1024                // threads

__global__ __launch_bounds__(1024) void pass_c_kernel(
    const __hip_bfloat16* __restrict__ C, const float* __restrict__ keys,
    const float* __restrict__ QT, const float* __restrict__ F,
    const float* __restrict__ tau_p, const float* __restrict__ lam_p,
    const unsigned char* __restrict__ warm_p, float* __restrict__ out)
{
    const int b = blockIdx.x, tid = threadIdx.x;
    __shared__ float redA[16], redB[16], redC[16];
    __shared__ unsigned hist[HB];
    __shared__ double cval[MAXC];
    __shared__ int cidx[MAXC];
    __shared__ int cnt;
    __shared__ float sh_thr, sh_lo, sh_iw;
    __shared__ int sh_done;
    __shared__ float sh_stat[3];
    __shared__ double topv[KMAX];
    __shared__ int topi[KMAX];

    const __hip_bfloat16* crow = C + (size_t)b * NKEYS;

    // ---- phase 1: mean / var / max (streaming short8) ----
    float sm = 0.f, sq = 0.f, mx = -2.f;
    for (int i = tid; i < NV8; i += CTH) {
        const short8 v8 = *reinterpret_cast<const short8*>(crow + i * 8);
        #pragma unroll
        for (int e = 0; e < 8; ++e) {
            const float v = bf16_up(v8[e]);
            sm += v; sq += v * v; mx = fmaxf(mx, v);
        }
    }
    #pragma unroll
    for (int off = 32; off > 0; off >>= 1) {
        sm += __shfl_down(sm, off);
        sq += __shfl_down(sq, off);
        mx = fmaxf(mx, __shfl_down(mx, off));
    }
    if ((tid & 63) == 0) { redA[tid >> 6] = sm; redB[tid >> 6] = sq; redC[tid >> 6] = mx; }
    __syncthreads();
    if (tid == 0) {
        float S1 = 0.f, S2 = 0.f, M = -2.f;
        #pragma unroll
        for (int i = 0; i < 16; ++i) { S1 += redA[i]; S2 += redB[i]; M = fmaxf(M, redC[i]); }
        const float mu = S1 / NKEYS;
        sh_stat[0] = mu;
        sh_stat[1] = sqrtf(fmaxf(S2 / NKEYS - mu * mu, 1e-12f));
        sh_stat[2] = M;
    }
    __syncthreads();
    const float mu = sh_stat[0], sg = sh_stat[1], rmax = sh_stat[2];

    // ---- phase 2: adaptive tail histogram + PARALLEL suffix scan ----
    for (int attempt = 0; attempt < 3; ++attempt) {
        if (tid == 0) {
            float lo = (attempt == 0) ? (mu + 2.5f * sg)
                     : (attempt == 1) ? mu : -1.1f;
            lo = fminf(lo, rmax - 1e-6f);
            const float range = fmaxf(rmax + 1e-6f - lo, 1e-6f);
            sh_lo = lo;
            sh_iw = (float)HB / range;
        }
        for (int i = tid; i < HB; i += CTH) hist[i] = 0u;
        __syncthreads();
        const float lo = sh_lo, iw = sh_iw;
        for (int i = tid; i < NV8; i += CTH) {
            const short8 v8 = *reinterpret_cast<const short8*>(crow + i * 8);
            #pragma unroll
            for (int e = 0; e < 8; ++e) {
                const float v = bf16_up(v8[e]);
                if (v >= lo) {
                    const int bin = min((int)((v - lo) * iw), HB - 1);
                    atomicAdd(&hist[bin], 1u);
                }
            }
        }
        __syncthreads();
        if (tid < 64) {
            unsigned csum = 0;
            #pragma unroll
            for (int j = 0; j < 16; ++j) csum += hist[tid * 16 + j];
            unsigned S = csum;                    // inclusive suffix over lanes
            #pragma unroll
            for (int off = 1; off < 64; off <<= 1) {
                const unsigned u = __shfl_down(S, off);
                if (tid + off < 64) S += u;
            }
            const unsigned long long mk = __ballot(S >= (unsigned)KMAX);
            if (mk == 0ull) {
                if (tid == 0) sh_done = 0;
            } else {
                const int cstar = 63 - __clzll(mk);
                const unsigned above = (cstar < 63) ? __shfl(S, cstar + 1) : 0u;
                unsigned v2 = (tid < 16) ? hist[cstar * 16 + tid] : 0u;
                unsigned S2 = v2;
                #pragma unroll
                for (int off = 1; off < 64; off <<= 1) {
                    const unsigned u = __shfl_down(S2, off);
                    if (tid + off < 64) S2 += u;
                }
                S2 += above;
                const unsigned long long mk2 = __ballot(S2 >= (unsigned)KMAX);
                const int hi = 63 - __clzll(mk2);
                const int t = cstar * 16 + hi;
                if (tid == 0) {
                    sh_thr = lo + (float)t / sh_iw - MARGIN;   // R6-identical expression
                    sh_done = 1;
                }
            }
        }
        __syncthreads();
        if (sh_done) break;
    }

    // ---- phase 3: compact candidates (streaming) ----
    if (tid == 0) cnt = 0;
    __syncthreads();
    const float ct = sh_thr;
    for (int i = tid; i < NV8; i += CTH) {
        const short8 v8 = *reinterpret_cast<const short8*>(crow + i * 8);
        #pragma unroll
        for (int e = 0; e < 8; ++e) {
            if (bf16_up(v8[e]) >= ct) {
                const int p = atomicAdd(&cnt, 1);
                if (p < MAXC) cidx[p] = i * 8 + e;
            }
        }
    }
    __syncthreads();
    const int m = min(cnt, MAXC);

    // ---- phase 4: fp64 exact re-rank, one candidate per wave (16 waves) ----
    const int wave = tid >> 6, lane = tid & 63;
    const int si = lane >> 3, kg = lane & 7;
    for (int c = wave; c < m; c += 16) {
        const int n = cidx[c];
        const float f = F[(size_t)si * NKEYS + n];
        const float* krow = keys + ((size_t)si * NKEYS + n) * DK + kg * 16;
        const float4 k0 = *reinterpret_cast<const float4*>(krow + 0);
        const float4 k1 = *reinterpret_cast<const float4*>(krow + 4);
        const float4 k2 = *reinterpret_cast<const float4*>(krow + 8);
        const float4 k3 = *reinterpret_cast<const float4*>(krow + 12);
        const float kf[16] = {k0.x, k0.y, k0.z, k0.w, k1.x, k1.y, k1.z, k1.w,
                              k2.x, k2.y, k2.z, k2.w, k3.x, k3.y, k3.z, k3.w};
        double acc = 0.0;
        #pragma unroll
        for (int j = 0; j < 16; ++j) {
            const float q = QT[(size_t)(si * DK + kg * 16 + j) * B_ + b];
            acc += (double)q * ((double)kf[j] * (double)f);
        }
        #pragma unroll
        for (int off = 1; off < 64; off <<= 1) acc += __shfl_xor(acc, off);
        if (lane == 0) cval[c] = acc;
    }
    __syncthreads();

    // ---- phase 5: single-wave exact top-32 (desc value, ties -> asc index) ----
    if (tid < 64) {
        for (int r = 0; r < KMAX; ++r) {
            double bv = -1e300; int bi = 0x7fffffff; int bp = -1;
            for (int c = tid; c < m; c += 64) {
                const double v = cval[c]; const int ix = cidx[c];
                if (v > bv || (v == bv && ix < bi)) { bv = v; bi = ix; bp = c; }
            }
            #pragma unroll
            for (int off = 32; off > 0; off >>= 1) {
                const double ov = __shfl_xor(bv, off);
                const int oi = __shfl_xor(bi, off);
                const int op = __shfl_xor(bp, off);
                if (ov > bv || (ov == bv && oi < bi)) { bv = ov; bi = oi; bp = op; }
            }
            if (tid == 0) { topv[r] = bv; topi[r] = bi; if (bp >= 0) cval[bp] = -1e301; }
        }
        if (tid == 0) {
            const float lamv = lam_p[0];
            const float tauv = tau_p[0];
            const bool warm = warm_p[0] != 0;
            float al[KMAX];
            float ssum = 0.f;
            if (warm) {
                const float x0 = (float)topv[0] / 0.1f;
                for (int i = 0; i < KMAX; ++i) {
                    const float e = expf((float)topv[i] / 0.1f - x0);
                    al[i] = e; ssum += e;
                }
            } else {
                for (int i = 0; i < KMAX; ++i) {
                    const float v = (float)topv[i];
                    const float g = 1.0f / (1.0f + expf(-(lamv * (v - tauv))));
                    const float rr = g * expf(v / 0.1f);
                    al[i] = rr; ssum += rr;
                }
            }
            for (int i = 0; i < KMAX; ++i) {
                out[b * KMAX + i] = al[i] / ssum;
                out[B_ * KMAX + b * KMAX + i] = (float)topi[i];
            }
        }
    }
}

// ---------------------------------------------------------------------------
extern "C" void kernel_launch(void* const* d_in, const int* in_sizes, int n_in,
                              void* d_out, int out_size, void* d_ws, size_t ws_size,
                              hipStream_t stream) {
    const float* z    = (const float*)d_in[0];
    const float* keys = (const float*)d_in[1];
    const float* wq   = (const float*)d_in[2];
    const float* aw   = (const float*)d_in[3];
    const float* tau  = (const float*)d_in[4];
    const float* lam  = (const float*)d_in[5];
    const unsigned char* warm = (const unsigned char*)d_in[6];
    float* out = (float*)d_out;

    char* ws = (char*)d_ws;
    float* QT           = (float*)ws;                          // @0       1.0 MB
    float* F            = (float*)(ws + (1 << 20));            // @1MB     3.2 MB
    __hip_bfloat16* Qb  = (__hip_bfloat16*)(ws + (8 << 20));   // @8MB     0.5 MB
    __hip_bfloat16* C   = (__hip_bfloat16*)(ws + ((size_t)232 << 20)); // @232MB 51.2 MB

    pass_a_kernel<<<dim3(B_, S_), 128, 0, stream>>>(z, wq, QT, Qb);
    pass_b2_kernel<<<dim3(NBLK), 512, 0, stream>>>(keys, aw, Qb, F, C);
    pass_c_kernel<<<dim3(B_), 1024, 0, stream>>>(C, keys, QT, F, tau, lam, warm, out);
}